// Round 6
// baseline (297.082 us; speedup 1.0000x reference)
//
#include <hip/hip_runtime.h>
#include <hip/hip_bf16.h>
#include <math.h>

#define B_    8
#define N_    9225
#define M_    4096
#define K_    32
#define HID_  64
#define DOUT_ 16

typedef __attribute__((ext_vector_type(8))) short short8;
typedef __attribute__((ext_vector_type(4))) float floatx4;
typedef __attribute__((ext_vector_type(2))) float f32x2;

static __device__ __forceinline__ short f2bf(float f) {
    __hip_bfloat16 h = __float2bfloat16(f);
    return __builtin_bit_cast(short, h);
}
static __device__ __forceinline__ f32x2 splat2(float v) { return (f32x2){v, v}; }
static __device__ __forceinline__ int bpermi(int src_bytes, int v) {
    return __builtin_amdgcn_ds_bpermute(src_bytes, v);
}
static __device__ __forceinline__ float bpermf(int src_bytes, float v) {
    return __builtin_bit_cast(float,
        __builtin_amdgcn_ds_bpermute(src_bytes, __builtin_bit_cast(int, v)));
}

// Sum over each 16-lane DPP row via row_shr tree; lane (row*16+15) holds the sum.
static __device__ __forceinline__ float row16_sum(float v) {
    int t;
    t = __builtin_amdgcn_update_dpp(0, __builtin_bit_cast(int, v), 0x111, 0xF, 0xF, true);
    v += __builtin_bit_cast(float, t);
    t = __builtin_amdgcn_update_dpp(0, __builtin_bit_cast(int, v), 0x112, 0xF, 0xF, true);
    v += __builtin_bit_cast(float, t);
    t = __builtin_amdgcn_update_dpp(0, __builtin_bit_cast(int, v), 0x114, 0xF, 0xF, true);
    v += __builtin_bit_cast(float, t);
    t = __builtin_amdgcn_update_dpp(0, __builtin_bit_cast(int, v), 0x118, 0xF, 0xF, true);
    v += __builtin_bit_cast(float, t);
    return v;
}

// gelu(x) ~ 0.5*x*(1 + tanh(z)), z = x*(0.79788456 + 0.035677408*x^2),
// tanh via Pade(5,4), clamped to [-1,1]. No v_exp.
static __device__ __forceinline__ f32x2 gelu2(f32x2 x) {
    const f32x2 xsq = x * x;
    const f32x2 t   = __builtin_elementwise_fma(xsq, splat2(0.035677408f), splat2(0.79788456f));
    const f32x2 z   = x * t;
    const f32x2 u   = z * z;
    const f32x2 a   = u + splat2(105.0f);
    const f32x2 nin = __builtin_elementwise_fma(u, a, splat2(945.0f));
    const f32x2 num = z * nin;
    const f32x2 bq  = __builtin_elementwise_fma(u, splat2(15.0f), splat2(420.0f));
    const f32x2 den = __builtin_elementwise_fma(u, bq, splat2(945.0f));
    const f32x2 r   = { __builtin_amdgcn_rcpf(den[0]), __builtin_amdgcn_rcpf(den[1]) };
    f32x2 th = num * r;
    th = __builtin_elementwise_min(__builtin_elementwise_max(th, splat2(-1.0f)), splat2(1.0f));
    const f32x2 hx = x * splat2(0.5f);
    return __builtin_elementwise_fma(hx, th, hx);
}

// Wave owns 2 rows. Dedup gather: lane g = (row g>>5, nbr g&31) loads
// nbr/y/weights once. Four phases ph=(it,h); per phase: bperm y/s into the
// (q,nlo) compute layout, h-stage (MFMA B-frag slots j=ch*32+q*8+jj),
// C' = W2^T x h^T (acc preloaded with b2), lane-local f*s epilogue.
// f_y gathers are software-pipelined one phase ahead (2-deep buffer) to cut
// live registers; __launch_bounds__(256,6) caps unified VGPR+AGPR at ~85
// to lift occupancy (R2-R5 stuck at 25% occ = latency-bound).
__global__ __launch_bounds__(256, 6) void it_kernel(
    const float* __restrict__ y,
    const float* __restrict__ x,
    const float* __restrict__ f_y,
    const float* __restrict__ weights,
    const float* __restrict__ W1,   // [4][64] row-major
    const float* __restrict__ b1,   // [64]
    const float* __restrict__ W2,   // [64][16] row-major
    const float* __restrict__ b2,   // [16]
    const int*   __restrict__ nbr,  // [B][M][K] int32
    float*       __restrict__ out)  // [B][M][16]
{
    const int tid  = threadIdx.x;
    const int lane = tid & 63;
    const int q    = lane >> 4;    // quad 0..3
    const int nlo  = lane & 15;    // neighbor-within-half; also c for W2 A-frag
    const int wave = blockIdx.x * 4 + (tid >> 6);
    const int row0 = wave * 2;             // both rows share the same batch b
    const int b    = row0 >> 12;           // M = 4096
    const int bbase = b * N_;

    // ---- dedup gather: lane g covers (row g>>5, neighbor g&31) ----
    const int r_g = lane >> 5, kk = lane & 31;
    const int raw = nbr[(size_t)(row0 + r_g) * K_ + kk];
    const int vld = raw >= 0;
    const int bn_g = bbase + (vld ? raw : 0);
    const float2 yvg = *(const float2*)(y + (size_t)bn_g * 2);
    const float  wg  = vld ? weights[bn_g] : 0.0f;

    const float2 xv0 = *(const float2*)(x + (size_t)row0 * 2);
    const float2 xv1 = *(const float2*)(x + (size_t)(row0 + 1) * 2);

    // ---- per-lane W1/b1 register slices (float2-packed) ----
    f32x2 w1r[2][4][4];   // [chunk][input dim][jj pair]
    f32x2 b1r[2][4];
    #pragma unroll
    for (int ch = 0; ch < 2; ++ch) {
        #pragma unroll
        for (int i = 0; i < 4; ++i) {
            const floatx4 a0 = *(const floatx4*)(W1 + i*64 + ch*32 + q*8);
            const floatx4 a1 = *(const floatx4*)(W1 + i*64 + ch*32 + q*8 + 4);
            w1r[ch][i][0] = (f32x2){a0[0], a0[1]};
            w1r[ch][i][1] = (f32x2){a0[2], a0[3]};
            w1r[ch][i][2] = (f32x2){a1[0], a1[1]};
            w1r[ch][i][3] = (f32x2){a1[2], a1[3]};
        }
        const floatx4 c0 = *(const floatx4*)(b1 + ch*32 + q*8);
        const floatx4 c1 = *(const floatx4*)(b1 + ch*32 + q*8 + 4);
        b1r[ch][0] = (f32x2){c0[0], c0[1]};
        b1r[ch][1] = (f32x2){c0[2], c0[3]};
        b1r[ch][2] = (f32x2){c1[0], c1[1]};
        b1r[ch][3] = (f32x2){c1[2], c1[3]};
    }

    // ---- W2 A-fragment: lane holds A[m=c=nlo][k=q*8+jj] = W2[j][nlo], bf16 ----
    short8 w2f[2];
    #pragma unroll
    for (int ch = 0; ch < 2; ++ch)
        #pragma unroll
        for (int jj = 0; jj < 8; ++jj)
            w2f[ch][jj] = f2bf(W2[(ch*32 + q*8 + jj) * DOUT_ + nlo]);

    const floatx4 b2v = *(const floatx4*)(b2 + q*4);

    // ---- phase pipeline: ph = it*2 + h; fv prefetched one phase ahead ----
    floatx4 fvbuf[2];
    {
        const int bn0 = bpermi(nlo << 2, bn_g);            // phase 0: it=0,h=0
        fvbuf[0] = *(const floatx4*)(f_y + (size_t)bn0 * 16 + q * 4);
    }

    float partial[4] = {0.f, 0.f, 0.f, 0.f};
    #pragma unroll
    for (int ph = 0; ph < 4; ++ph) {
        const int it = ph >> 1, h = ph & 1;
        const int src = ((it << 5) + (h << 4) + nlo) << 2;

        if (ph < 3) {   // prefetch next phase's f_y
            const int src_n = (((ph + 1) >> 1) << 7) + (((ph + 1) & 1) << 6) + (nlo << 2);
            const int bn_n  = bpermi(src_n, bn_g);
            fvbuf[(ph + 1) & 1] = *(const floatx4*)(f_y + (size_t)bn_n * 16 + q * 4);
        }

        // redistribute this phase's y / weight to (q,nlo) layout
        f32x2 yv;
        yv[0] = bpermf(src, yvg.x);
        yv[1] = bpermf(src, yvg.y);
        const float s = bpermf(src, wg);
        const float2 xv = it ? xv1 : xv0;

        short8 hf[2];
        #pragma unroll
        for (int ch = 0; ch < 2; ++ch) {
            #pragma unroll
            for (int p = 0; p < 4; ++p) {
                f32x2 hin = b1r[ch][p];
                hin = __builtin_elementwise_fma(splat2(yv[0]), w1r[ch][0][p], hin);
                hin = __builtin_elementwise_fma(splat2(yv[1]), w1r[ch][1][p], hin);
                hin = __builtin_elementwise_fma(splat2(xv.x),  w1r[ch][2][p], hin);
                hin = __builtin_elementwise_fma(splat2(xv.y),  w1r[ch][3][p], hin);
                const f32x2 g = gelu2(hin);
                hf[ch][2*p]     = f2bf(g[0]);
                hf[ch][2*p + 1] = f2bf(g[1]);
            }
        }
        // acc preloaded with b2 (broadcast across cols = neighbors)
        floatx4 acc = b2v;
        acc = __builtin_amdgcn_mfma_f32_16x16x32_bf16(w2f[0], hf[0], acc, 0, 0, 0);
        acc = __builtin_amdgcn_mfma_f32_16x16x32_bf16(w2f[1], hf[1], acc, 0, 0, 0);
        #pragma unroll
        for (int r4 = 0; r4 < 4; ++r4)
            partial[r4] = fmaf(acc[r4], fvbuf[ph & 1][r4] * s, partial[r4]);

        if (h == 1) {   // finished a row: reduce over 16 neighbors, store
            #pragma unroll
            for (int r4 = 0; r4 < 4; ++r4)
                partial[r4] = row16_sum(partial[r4]);
            if (nlo == 15) {
                floatx4 o = {partial[0], partial[1], partial[2], partial[3]};
                *(floatx4*)(out + (size_t)(row0 + it) * DOUT_ + q*4) = o;
            }
            #pragma unroll
            for (int r4 = 0; r4 < 4; ++r4) partial[r4] = 0.f;
        }
    }
}

extern "C" void kernel_launch(void* const* d_in, const int* in_sizes, int n_in,
                              void* d_out, int out_size, void* d_ws, size_t ws_size,
                              hipStream_t stream) {
    const float* y   = (const float*)d_in[0];
    const float* x   = (const float*)d_in[1];
    const float* f_y = (const float*)d_in[2];
    const float* w   = (const float*)d_in[3];
    const float* W1  = (const float*)d_in[4];
    const float* b1  = (const float*)d_in[5];
    const float* W2  = (const float*)d_in[6];
    const float* b2  = (const float*)d_in[7];
    const int*   nbr = (const int*)d_in[8];
    float* out = (float*)d_out;

    // 32768 rows / (4 waves * 2 rows) = 4096 blocks
    dim3 grid(B_ * M_ / 8), block(256);
    hipLaunchKernelGGL(it_kernel, grid, block, 0, stream,
                       y, x, f_y, w, W1, b1, W2, b2, nbr, out);
}

// Round 7
// 215.475 us; speedup vs baseline: 1.3787x; 1.3787x over previous
//
#include <hip/hip_runtime.h>
#include <hip/hip_bf16.h>
#include <math.h>

#define B_    8
#define N_    9225
#define M_    4096
#define K_    32
#define HID_  64
#define DOUT_ 16

typedef __attribute__((ext_vector_type(8))) short short8;
typedef __attribute__((ext_vector_type(4))) float floatx4;
typedef __attribute__((ext_vector_type(2))) float f32x2;

static __device__ __forceinline__ short f2bf(float f) {
    __hip_bfloat16 h = __float2bfloat16(f);
    return __builtin_bit_cast(short, h);
}
static __device__ __forceinline__ f32x2 splat2(float v) { return (f32x2){v, v}; }
static __device__ __forceinline__ int bpermi(int src_bytes, int v) {
    return __builtin_amdgcn_ds_bpermute(src_bytes, v);
}
static __device__ __forceinline__ float bpermf(int src_bytes, float v) {
    return __builtin_bit_cast(float,
        __builtin_amdgcn_ds_bpermute(src_bytes, __builtin_bit_cast(int, v)));
}

// Sum over each 16-lane DPP row via row_shr tree; lane (row*16+15) holds the sum.
static __device__ __forceinline__ float row16_sum(float v) {
    int t;
    t = __builtin_amdgcn_update_dpp(0, __builtin_bit_cast(int, v), 0x111, 0xF, 0xF, true);
    v += __builtin_bit_cast(float, t);
    t = __builtin_amdgcn_update_dpp(0, __builtin_bit_cast(int, v), 0x112, 0xF, 0xF, true);
    v += __builtin_bit_cast(float, t);
    t = __builtin_amdgcn_update_dpp(0, __builtin_bit_cast(int, v), 0x114, 0xF, 0xF, true);
    v += __builtin_bit_cast(float, t);
    t = __builtin_amdgcn_update_dpp(0, __builtin_bit_cast(int, v), 0x118, 0xF, 0xF, true);
    v += __builtin_bit_cast(float, t);
    return v;
}

// LUT gelu: glut[u] = Phi(x_u), x_u = (u-1024)/256, u in [0,2048).
// gelu(x) = x * Phi(x); index = clamp(round(x*256+1024)) via fma+med3+cvt.
// Out-of-range clamps to Phi=~0 (left) / ~1 (right) which is exact behavior.
// Nearest-neighbor err on h <= ~5e-4 (max of |x * Phi'(x)| * step/2), far
// below the bf16 quantization already applied to h. ~10 VALU cyc + 1 ds_read
// per eval vs ~36 cyc for the Pade tanh form.
static __device__ __forceinline__ float gelu_lut(const float (&lut)[2048], float v) {
    float t = fmaf(v, 256.0f, 1024.5f);
    t = __builtin_amdgcn_fmed3f(t, 0.0f, 2047.0f);
    return v * lut[(unsigned)t];
}

// Wave owns 2 rows. Dedup gather: lane g = (row g>>5, nbr g&31) loads
// nbr/y/weights once. Four phases ph=(it,h); per phase: bperm y/s into the
// (q,nlo) compute layout, h-stage (MFMA B-frag slots j=ch*32+q*8+jj),
// C' = W2^T x h^T (acc preloaded with b2), lane-local f*s epilogue.
// f_y gathers software-pipelined one phase ahead. __launch_bounds__(256,4):
// R6 proved occupancy is register-capped (AGPR side of the unified file) --
// 6 waves/EU spilled (40 VGPR + 489MB scratch), 4 waves/EU = 128 regs fits
// the ~90-reg liveness without spill.
__global__ __launch_bounds__(256, 4) void it_kernel(
    const float* __restrict__ y,
    const float* __restrict__ x,
    const float* __restrict__ f_y,
    const float* __restrict__ weights,
    const float* __restrict__ W1,   // [4][64] row-major
    const float* __restrict__ b1,   // [64]
    const float* __restrict__ W2,   // [64][16] row-major
    const float* __restrict__ b2,   // [16]
    const int*   __restrict__ nbr,  // [B][M][K] int32
    float*       __restrict__ out)  // [B][M][16]
{
    __shared__ float glut[2048];

    const int tid  = threadIdx.x;
    // ---- build gelu LUT (8 entries/thread), before any LDS-data use ----
    #pragma unroll
    for (int i = 0; i < 8; ++i) {
        const int u = tid + (i << 8);
        const float xx = ((float)u - 1024.0f) * (1.0f / 256.0f);
        glut[u] = 0.5f * (1.0f + erff(xx * 0.70710678118654752f));
    }

    const int lane = tid & 63;
    const int q    = lane >> 4;    // quad 0..3
    const int nlo  = lane & 15;    // neighbor-within-half; also c for W2 A-frag
    const int wave = blockIdx.x * 4 + (tid >> 6);
    const int row0 = wave * 2;             // both rows share the same batch b
    const int b    = row0 >> 12;           // M = 4096
    const int bbase = b * N_;

    // ---- dedup gather: lane g covers (row g>>5, neighbor g&31) ----
    const int r_g = lane >> 5, kk = lane & 31;
    const int raw = nbr[(size_t)(row0 + r_g) * K_ + kk];
    const int vld = raw >= 0;
    const int bn_g = bbase + (vld ? raw : 0);
    const float2 yvg = *(const float2*)(y + (size_t)bn_g * 2);
    const float  wg  = vld ? weights[bn_g] : 0.0f;

    const float2 xv0 = *(const float2*)(x + (size_t)row0 * 2);
    const float2 xv1 = *(const float2*)(x + (size_t)(row0 + 1) * 2);

    // ---- per-lane W1/b1 register slices (float2-packed) ----
    f32x2 w1r[2][4][4];   // [chunk][input dim][jj pair]
    f32x2 b1r[2][4];
    #pragma unroll
    for (int ch = 0; ch < 2; ++ch) {
        #pragma unroll
        for (int i = 0; i < 4; ++i) {
            const floatx4 a0 = *(const floatx4*)(W1 + i*64 + ch*32 + q*8);
            const floatx4 a1 = *(const floatx4*)(W1 + i*64 + ch*32 + q*8 + 4);
            w1r[ch][i][0] = (f32x2){a0[0], a0[1]};
            w1r[ch][i][1] = (f32x2){a0[2], a0[3]};
            w1r[ch][i][2] = (f32x2){a1[0], a1[1]};
            w1r[ch][i][3] = (f32x2){a1[2], a1[3]};
        }
        const floatx4 c0 = *(const floatx4*)(b1 + ch*32 + q*8);
        const floatx4 c1 = *(const floatx4*)(b1 + ch*32 + q*8 + 4);
        b1r[ch][0] = (f32x2){c0[0], c0[1]};
        b1r[ch][1] = (f32x2){c0[2], c0[3]};
        b1r[ch][2] = (f32x2){c1[0], c1[1]};
        b1r[ch][3] = (f32x2){c1[2], c1[3]};
    }

    // ---- W2 A-fragment: lane holds A[m=c=nlo][k=q*8+jj] = W2[j][nlo], bf16 ----
    short8 w2f[2];
    #pragma unroll
    for (int ch = 0; ch < 2; ++ch)
        #pragma unroll
        for (int jj = 0; jj < 8; ++jj)
            w2f[ch][jj] = f2bf(W2[(ch*32 + q*8 + jj) * DOUT_ + nlo]);

    const floatx4 b2v = *(const floatx4*)(b2 + q*4);

    // ---- phase pipeline: ph = it*2 + h; fv prefetched one phase ahead ----
    floatx4 fvbuf[2];
    {
        const int bn0 = bpermi(nlo << 2, bn_g);            // phase 0: it=0,h=0
        fvbuf[0] = *(const floatx4*)(f_y + (size_t)bn0 * 16 + q * 4);
    }

    __syncthreads();   // LUT visible to all 4 waves

    float partial[4] = {0.f, 0.f, 0.f, 0.f};
    #pragma unroll
    for (int ph = 0; ph < 4; ++ph) {
        const int it = ph >> 1, h = ph & 1;
        const int src = ((it << 5) + (h << 4) + nlo) << 2;

        if (ph < 3) {   // prefetch next phase's f_y
            const int src_n = (((ph + 1) >> 1) << 7) + (((ph + 1) & 1) << 6) + (nlo << 2);
            const int bn_n  = bpermi(src_n, bn_g);
            fvbuf[(ph + 1) & 1] = *(const floatx4*)(f_y + (size_t)bn_n * 16 + q * 4);
        }

        // redistribute this phase's y / weight to (q,nlo) layout
        f32x2 yv;
        yv[0] = bpermf(src, yvg.x);
        yv[1] = bpermf(src, yvg.y);
        const float s = bpermf(src, wg);
        const float2 xv = it ? xv1 : xv0;

        short8 hf[2];
        #pragma unroll
        for (int ch = 0; ch < 2; ++ch) {
            #pragma unroll
            for (int p = 0; p < 4; ++p) {
                f32x2 hin = b1r[ch][p];
                hin = __builtin_elementwise_fma(splat2(yv[0]), w1r[ch][0][p], hin);
                hin = __builtin_elementwise_fma(splat2(yv[1]), w1r[ch][1][p], hin);
                hin = __builtin_elementwise_fma(splat2(xv.x),  w1r[ch][2][p], hin);
                hin = __builtin_elementwise_fma(splat2(xv.y),  w1r[ch][3][p], hin);
                hf[ch][2*p]     = f2bf(gelu_lut(glut, hin[0]));
                hf[ch][2*p + 1] = f2bf(gelu_lut(glut, hin[1]));
            }
        }
        // acc preloaded with b2 (broadcast across cols = neighbors)
        floatx4 acc = b2v;
        acc = __builtin_amdgcn_mfma_f32_16x16x32_bf16(w2f[0], hf[0], acc, 0, 0, 0);
        acc = __builtin_amdgcn_mfma_f32_16x16x32_bf16(w2f[1], hf[1], acc, 0, 0, 0);
        #pragma unroll
        for (int r4 = 0; r4 < 4; ++r4)
            partial[r4] = fmaf(acc[r4], fvbuf[ph & 1][r4] * s, partial[r4]);

        if (h == 1) {   // finished a row: reduce over 16 neighbors, store
            #pragma unroll
            for (int r4 = 0; r4 < 4; ++r4)
                partial[r4] = row16_sum(partial[r4]);
            if (nlo == 15) {
                floatx4 o = {partial[0], partial[1], partial[2], partial[3]};
                *(floatx4*)(out + (size_t)(row0 + it) * DOUT_ + q*4) = o;
            }
            #pragma unroll
            for (int r4 = 0; r4 < 4; ++r4) partial[r4] = 0.f;
        }
    }
}

extern "C" void kernel_launch(void* const* d_in, const int* in_sizes, int n_in,
                              void* d_out, int out_size, void* d_ws, size_t ws_size,
                              hipStream_t stream) {
    const float* y   = (const float*)d_in[0];
    const float* x   = (const float*)d_in[1];
    const float* f_y = (const float*)d_in[2];
    const float* w   = (const float*)d_in[3];
    const float* W1  = (const float*)d_in[4];
    const float* b1  = (const float*)d_in[5];
    const float* W2  = (const float*)d_in[6];
    const float* b2  = (const float*)d_in[7];
    const int*   nbr = (const int*)d_in[8];
    float* out = (float*)d_out;

    // 32768 rows / (4 waves * 2 rows) = 4096 blocks
    dim3 grid(B_ * M_ / 8), block(256);
    hipLaunchKernelGGL(it_kernel, grid, block, 0, stream,
                       y, x, f_y, w, W1, b1, W2, b2, nbr, out);
}

// Round 8
// 106.481 us; speedup vs baseline: 2.7900x; 2.0236x over previous
//
#include <hip/hip_runtime.h>
#include <hip/hip_bf16.h>
#include <math.h>

#define B_    8
#define N_    9225
#define M_    4096
#define K_    32
#define HID_  64
#define DOUT_ 16

typedef __attribute__((ext_vector_type(8))) short short8;
typedef __attribute__((ext_vector_type(4))) float floatx4;
typedef __attribute__((ext_vector_type(2))) float f32x2;

static __device__ __forceinline__ short f2bf(float f) {
    __hip_bfloat16 h = __float2bfloat16(f);
    return __builtin_bit_cast(short, h);
}
static __device__ __forceinline__ f32x2 splat2(float v) { return (f32x2){v, v}; }
static __device__ __forceinline__ int bpermi(int src_bytes, int v) {
    return __builtin_amdgcn_ds_bpermute(src_bytes, v);
}
static __device__ __forceinline__ float bpermf(int src_bytes, float v) {
    return __builtin_bit_cast(float,
        __builtin_amdgcn_ds_bpermute(src_bytes, __builtin_bit_cast(int, v)));
}

// Sum over each 16-lane DPP row via row_shr tree; lane (row*16+15) holds the sum.
static __device__ __forceinline__ float row16_sum(float v) {
    int t;
    t = __builtin_amdgcn_update_dpp(0, __builtin_bit_cast(int, v), 0x111, 0xF, 0xF, true);
    v += __builtin_bit_cast(float, t);
    t = __builtin_amdgcn_update_dpp(0, __builtin_bit_cast(int, v), 0x112, 0xF, 0xF, true);
    v += __builtin_bit_cast(float, t);
    t = __builtin_amdgcn_update_dpp(0, __builtin_bit_cast(int, v), 0x114, 0xF, 0xF, true);
    v += __builtin_bit_cast(float, t);
    t = __builtin_amdgcn_update_dpp(0, __builtin_bit_cast(int, v), 0x118, 0xF, 0xF, true);
    v += __builtin_bit_cast(float, t);
    return v;
}

// gelu(x) ~ 0.5*x*(1 + tanh(z)), z = x*(0.79788456 + 0.035677408*x^2),
// tanh via Pade(5,4), clamped to [-1,1]. No v_exp. (Validated R4/R5.)
static __device__ __forceinline__ f32x2 gelu2(f32x2 x) {
    const f32x2 xsq = x * x;
    const f32x2 t   = __builtin_elementwise_fma(xsq, splat2(0.035677408f), splat2(0.79788456f));
    const f32x2 z   = x * t;
    const f32x2 u   = z * z;
    const f32x2 a   = u + splat2(105.0f);
    const f32x2 nin = __builtin_elementwise_fma(u, a, splat2(945.0f));
    const f32x2 num = z * nin;
    const f32x2 bq  = __builtin_elementwise_fma(u, splat2(15.0f), splat2(420.0f));
    const f32x2 den = __builtin_elementwise_fma(u, bq, splat2(945.0f));
    const f32x2 r   = { __builtin_amdgcn_rcpf(den[0]), __builtin_amdgcn_rcpf(den[1]) };
    f32x2 th = num * r;
    th = __builtin_elementwise_min(__builtin_elementwise_max(th, splat2(-1.0f)), splat2(1.0f));
    const f32x2 hx = x * splat2(0.5f);
    return __builtin_elementwise_fma(hx, th, hx);
}

// Wave owns 2 rows. Dedup gather: lane g = (row g>>5, nbr g&31) loads
// nbr/y/weights once; ds_bpermute redistributes to the (q,nlo) compute
// layout per phase. h-stage reads W1/b1 from LDS (staged once) instead of a
// 72-VGPR register cache -- R6/R7 proved occupancy was register-capped and
// forcing bounds without cutting liveness just spilled (489 MB scratch).
// Per-quad LDS addresses hit banks {0,8,16,24}: conflict-free broadcast.
// C' = W2^T x h^T via mfma_16x16x32_bf16 (acc preloaded with b2); col = own
// neighbor -> lane-local f*s epilogue, DPP row-sum, lane15 stores.
__global__ __launch_bounds__(256) void it_kernel(
    const float* __restrict__ y,
    const float* __restrict__ x,
    const float* __restrict__ f_y,
    const float* __restrict__ weights,
    const float* __restrict__ W1,   // [4][64] row-major
    const float* __restrict__ b1,   // [64]
    const float* __restrict__ W2,   // [64][16] row-major
    const float* __restrict__ b2,   // [16]
    const int*   __restrict__ nbr,  // [B][M][K] int32
    float*       __restrict__ out)  // [B][M][16]
{
    __shared__ float W1L[4][64];
    __shared__ float b1L[64];

    const int tid  = threadIdx.x;
    if (tid < 256) W1L[tid >> 6][tid & 63] = W1[tid];
    if (tid < 64)  b1L[tid] = b1[tid];

    const int lane = tid & 63;
    const int q    = lane >> 4;    // quad 0..3
    const int nlo  = lane & 15;    // neighbor-within-half; also c for W2 A-frag
    const int wave = blockIdx.x * 4 + (tid >> 6);
    const int row0 = wave * 2;             // both rows share the same batch b
    const int b    = row0 >> 12;           // M = 4096
    const int bbase = b * N_;

    // ---- dedup gather: lane g covers (row g>>5, neighbor g&31) ----
    const int r_g = lane >> 5, kk = lane & 31;
    const int raw = nbr[(size_t)(row0 + r_g) * K_ + kk];
    const int vld = raw >= 0;
    const int bn_g = bbase + (vld ? raw : 0);
    const float2 yvg = *(const float2*)(y + (size_t)bn_g * 2);
    const float  wg  = vld ? weights[bn_g] : 0.0f;

    const float2 xv0 = *(const float2*)(x + (size_t)row0 * 2);
    const float2 xv1 = *(const float2*)(x + (size_t)(row0 + 1) * 2);

    // ---- W2 A-fragment: lane holds A[m=c=nlo][k=q*8+jj] = W2[j][nlo], bf16 ----
    short8 w2f[2];
    #pragma unroll
    for (int ch = 0; ch < 2; ++ch)
        #pragma unroll
        for (int jj = 0; jj < 8; ++jj)
            w2f[ch][jj] = f2bf(W2[(ch*32 + q*8 + jj) * DOUT_ + nlo]);

    const floatx4 b2v = *(const floatx4*)(b2 + q*4);

    // ---- phase pipeline: ph = it*2 + h; fv prefetched one phase ahead ----
    floatx4 fvbuf[2];
    {
        const int bn0 = bpermi(nlo << 2, bn_g);            // phase 0: it=0,h=0
        fvbuf[0] = *(const floatx4*)(f_y + (size_t)bn0 * 16 + q * 4);
    }

    __syncthreads();   // W1L/b1L visible to all 4 waves

    float partial[4] = {0.f, 0.f, 0.f, 0.f};
    #pragma unroll
    for (int ph = 0; ph < 4; ++ph) {
        const int it = ph >> 1, h = ph & 1;
        const int src = ((it << 5) + (h << 4) + nlo) << 2;

        if (ph < 3) {   // prefetch next phase's f_y
            const int src_n = (((ph + 1) >> 1) << 7) + (((ph + 1) & 1) << 6) + (nlo << 2);
            const int bn_n  = bpermi(src_n, bn_g);
            fvbuf[(ph + 1) & 1] = *(const floatx4*)(f_y + (size_t)bn_n * 16 + q * 4);
        }

        // redistribute this phase's y / weight to (q,nlo) layout
        f32x2 yv;
        yv[0] = bpermf(src, yvg.x);
        yv[1] = bpermf(src, yvg.y);
        const float s = bpermf(src, wg);
        const float2 xv = it ? xv1 : xv0;

        short8 hf[2];
        #pragma unroll
        for (int ch = 0; ch < 2; ++ch) {
            #pragma unroll
            for (int p = 0; p < 4; ++p) {
                const int j = ch*32 + q*8 + 2*p;
                f32x2 hin = *(const f32x2*)&b1L[j];
                hin = __builtin_elementwise_fma(splat2(yv[0]), *(const f32x2*)&W1L[0][j], hin);
                hin = __builtin_elementwise_fma(splat2(yv[1]), *(const f32x2*)&W1L[1][j], hin);
                hin = __builtin_elementwise_fma(splat2(xv.x),  *(const f32x2*)&W1L[2][j], hin);
                hin = __builtin_elementwise_fma(splat2(xv.y),  *(const f32x2*)&W1L[3][j], hin);
                const f32x2 g = gelu2(hin);
                hf[ch][2*p]     = f2bf(g[0]);
                hf[ch][2*p + 1] = f2bf(g[1]);
            }
        }
        // acc preloaded with b2 (broadcast across cols = neighbors)
        floatx4 acc = b2v;
        acc = __builtin_amdgcn_mfma_f32_16x16x32_bf16(w2f[0], hf[0], acc, 0, 0, 0);
        acc = __builtin_amdgcn_mfma_f32_16x16x32_bf16(w2f[1], hf[1], acc, 0, 0, 0);
        #pragma unroll
        for (int r4 = 0; r4 < 4; ++r4)
            partial[r4] = fmaf(acc[r4], fvbuf[ph & 1][r4] * s, partial[r4]);

        if (h == 1) {   // finished a row: reduce over 16 neighbors, store
            #pragma unroll
            for (int r4 = 0; r4 < 4; ++r4)
                partial[r4] = row16_sum(partial[r4]);
            if (nlo == 15) {
                floatx4 o = {partial[0], partial[1], partial[2], partial[3]};
                *(floatx4*)(out + (size_t)(row0 + it) * DOUT_ + q*4) = o;
            }
            #pragma unroll
            for (int r4 = 0; r4 < 4; ++r4) partial[r4] = 0.f;
        }
    }
}

extern "C" void kernel_launch(void* const* d_in, const int* in_sizes, int n_in,
                              void* d_out, int out_size, void* d_ws, size_t ws_size,
                              hipStream_t stream) {
    const float* y   = (const float*)d_in[0];
    const float* x   = (const float*)d_in[1];
    const float* f_y = (const float*)d_in[2];
    const float* w   = (const float*)d_in[3];
    const float* W1  = (const float*)d_in[4];
    const float* b1  = (const float*)d_in[5];
    const float* W2  = (const float*)d_in[6];
    const float* b2  = (const float*)d_in[7];
    const int*   nbr = (const int*)d_in[8];
    float* out = (float*)d_out;

    // 32768 rows / (4 waves * 2 rows) = 4096 blocks
    dim3 grid(B_ * M_ / 8), block(256);
    hipLaunchKernelGGL(it_kernel, grid, block, 0, stream,
                       y, x, f_y, w, W1, b1, W2, b2, nbr, out);
}